// Round 4
// baseline (518.207 us; speedup 1.0000x reference)
//
#include <hip/hip_runtime.h>
#include <hip/hip_bf16.h>

typedef __attribute__((ext_vector_type(8))) short bf16x8;
typedef __attribute__((ext_vector_type(4))) short bf16x4;
typedef __attribute__((ext_vector_type(4))) float floatx4;
typedef unsigned short u16;
typedef unsigned int u32;

#define DM 1024
#define SEQ 4096
#define NH 16
#define HD 64
#define CHUNK 128

__device__ __forceinline__ float bf2f(u16 x) {
    u32 u = ((u32)x) << 16;
    return __builtin_bit_cast(float, u);
}
__device__ __forceinline__ u16 f2bf(float f) {
    u32 u = __builtin_bit_cast(u32, f);
    u32 r = u + 0x7FFF + ((u >> 16) & 1);
    return (u16)(r >> 16);
}
// load 8 contiguous f32, round to bf16x8
__device__ __forceinline__ bf16x8 cvt8(const float* p) {
    floatx4 a = *(const floatx4*)p;
    floatx4 b = *(const floatx4*)(p + 4);
    bf16x8 r;
    r[0] = (short)f2bf(a[0]); r[1] = (short)f2bf(a[1]);
    r[2] = (short)f2bf(a[2]); r[3] = (short)f2bf(a[3]);
    r[4] = (short)f2bf(b[0]); r[5] = (short)f2bf(b[1]);
    r[6] = (short)f2bf(b[2]); r[7] = (short)f2bf(b[3]);
    return r;
}

// ---------------------------------------------------------------------------
// GEMM: Y = A(MxK) @ W(NxK)^T + bias.   A,W,bias dtypes per MODE:
// MODE 0: A=f32 x, out = phi(.) -> bf16 head-major plane (Q,K)
// MODE 1: A=f32 x, out -> bf16 head-major plane (V)
// MODE 2: A=bf16 head-major plane (attn out), out -> f32 d_out slice
// W,bias always f32. 128x128 tile, BK=64, 4 waves, mfma 16x16x32 bf16.
// Register staging (global->VGPR(+cvt)->ds_write_b128), XOR-granule swizzle
// applied on the GLOBAL address so LDS reads are conflict-benign.
// ---------------------------------------------------------------------------
template <int MODE>
__global__ __launch_bounds__(256, 1) void gemm_k(
    const void* __restrict__ Av, const float* __restrict__ W,
    const float* __restrict__ bias, void* __restrict__ Yv)
{
    __shared__ __align__(16) u16 aSh[128 * 64];
    __shared__ __align__(16) u16 bSh[128 * 64];
    int t = threadIdx.x, lane = t & 63, w = t >> 6;
    int q = lane >> 4, ln = lane & 15;
    int wm = (w & 1) * 64, wn = (w >> 1) * 64;
    int m0 = blockIdx.x * 128, n0 = blockIdx.y * 128;
    floatx4 acc[4][4] = {};

    for (int k0 = 0; k0 < DM; k0 += 64) {
        bf16x8 areg[4], breg[4];
#pragma unroll
        for (int i = 0; i < 4; ++i) {
            int gi = i * 256 + t;
            int r = gi >> 3;
            int c = (gi & 7) ^ (r & 7);
            if (MODE == 2) {
                int rr = m0 + r;  // plane: ((bl*16+head)*4096+s)*64+dl
                const u16* asrc = (const u16*)Av
                    + (((size_t)((rr >> 12) * NH + (k0 >> 6))) << 18)
                    + (size_t)((rr & 4095) << 6) + (size_t)(c * 8);
                areg[i] = *(const bf16x8*)asrc;
            } else {
                areg[i] = cvt8((const float*)Av + (size_t)(m0 + r) * DM + k0 + c * 8);
            }
            breg[i] = cvt8(W + (size_t)(n0 + r) * DM + k0 + c * 8);
        }
        __syncthreads();  // previous iteration's readers done
#pragma unroll
        for (int i = 0; i < 4; ++i) {
            int gi = i * 256 + t;
            *(bf16x8*)&aSh[gi * 8] = areg[i];
            *(bf16x8*)&bSh[gi * 8] = breg[i];
        }
        __syncthreads();
#pragma unroll
        for (int ks = 0; ks < 2; ++ks) {
            int cg = ks * 4 + q;
            bf16x8 af[4], bfv[4];
#pragma unroll
            for (int tm = 0; tm < 4; ++tm) {
                int m = wm + tm * 16 + ln;
                af[tm] = *(const bf16x8*)&aSh[(m * 8 + (cg ^ (m & 7))) * 8];
            }
#pragma unroll
            for (int tn = 0; tn < 4; ++tn) {
                int n = wn + tn * 16 + ln;
                bfv[tn] = *(const bf16x8*)&bSh[(n * 8 + (cg ^ (n & 7))) * 8];
            }
#pragma unroll
            for (int tm = 0; tm < 4; ++tm)
#pragma unroll
                for (int tn = 0; tn < 4; ++tn)
                    acc[tm][tn] = __builtin_amdgcn_mfma_f32_16x16x32_bf16(
                        af[tm], bfv[tn], acc[tm][tn], 0, 0, 0);
        }
    }
    // Epilogue. C/D layout: col = lane&15, row = quad*4 + reg (m89-verified).
#pragma unroll
    for (int tn = 0; tn < 4; ++tn) {
        int gn = n0 + wn + tn * 16 + ln;
        float bb = bias[gn];
#pragma unroll
        for (int tm = 0; tm < 4; ++tm) {
            int gmb = wm + tm * 16 + q * 4 + m0;
#pragma unroll
            for (int r = 0; r < 4; ++r) {
                int gm = gmb + r;
                float v = acc[tm][tn][r] + bb;
                if (MODE == 0) v = (v > 0.f) ? (v + 1.f) : __expf(v);
                if (MODE <= 1) {
                    int batch = gm >> 12, s = gm & 4095;
                    int head = gn >> 6, dl = gn & 63;
                    ((u16*)Yv)[(((size_t)batch * NH + head) * SEQ + s) * HD + dl] = f2bf(v);
                } else {
                    ((float*)Yv)[(size_t)gm * DM + gn] = v;
                }
            }
        }
    }
}

// ---------------------------------------------------------------------------
// Per (head,chunk): Sc[d][e] = sum_r K[r][d]*V[r][e] (bf16); Zc[d]=sum_r K[r][d]
// ---------------------------------------------------------------------------
__global__ __launch_bounds__(256, 1) void chunk_stats_k(
    const u16* __restrict__ Kh, const u16* __restrict__ Vh,
    u16* __restrict__ Sc, float* __restrict__ Zc)
{
    __shared__ __align__(16) u16 kSh[128 * 64];
    __shared__ __align__(16) u16 vSh[128 * 64];
    int t = threadIdx.x;
    int bhc = blockIdx.x;
    const u16* Kb = Kh + ((size_t)(bhc >> 5) * SEQ + (size_t)(bhc & 31) * CHUNK) * HD;
    const u16* Vb = Vh + ((size_t)(bhc >> 5) * SEQ + (size_t)(bhc & 31) * CHUNK) * HD;
#pragma unroll
    for (int i = 0; i < 4; ++i) {
        int g = i * 256 + t;
        *(bf16x8*)&kSh[g * 8] = *(const bf16x8*)&Kb[(size_t)g * 8];
        *(bf16x8*)&vSh[g * 8] = *(const bf16x8*)&Vb[(size_t)g * 8];
    }
    __syncthreads();
    int eg = t & 15, dg = t >> 4;
    float acc[4][4] = {};
#pragma unroll 4
    for (int r = 0; r < 128; ++r) {
        bf16x4 kq = *(const bf16x4*)&kSh[r * 64 + dg * 4];
        bf16x4 vq = *(const bf16x4*)&vSh[r * 64 + eg * 4];
        float kf[4], vf[4];
#pragma unroll
        for (int i = 0; i < 4; ++i) { kf[i] = bf2f((u16)kq[i]); vf[i] = bf2f((u16)vq[i]); }
#pragma unroll
        for (int a = 0; a < 4; ++a)
#pragma unroll
            for (int b = 0; b < 4; ++b) acc[a][b] += kf[a] * vf[b];
    }
    u16* So = Sc + (size_t)bhc * HD * HD;
#pragma unroll
    for (int a = 0; a < 4; ++a) {
        bf16x4 sv;
#pragma unroll
        for (int b = 0; b < 4; ++b) sv[b] = (short)f2bf(acc[a][b]);
        *(bf16x4*)&So[(dg * 4 + a) * HD + eg * 4] = sv;
    }
    if (t < 64) {
        float z = 0.f;
        for (int r = 0; r < 128; ++r) z += bf2f(kSh[r * 64 + t]);
        Zc[(size_t)bhc * HD + t] = z;
    }
}

// ---------------------------------------------------------------------------
// Exclusive prefix over 32 chunks (per bh). grid (nbh, 33).
// ---------------------------------------------------------------------------
__global__ void prefix_k(u16* __restrict__ Sc, float* __restrict__ Zc)
{
    int bh = blockIdx.x, y = blockIdx.y, t = threadIdx.x;
    if (y < 32) {
        size_t base = (size_t)bh * 32 * 4096 + y * 128 + t;
        float run = 0.f;
#pragma unroll
        for (int c = 0; c < 32; ++c) {
            float cur = bf2f(Sc[base + (size_t)c * 4096]);
            Sc[base + (size_t)c * 4096] = f2bf(run);
            run += cur;
        }
    } else if (t < 64) {
        size_t base = (size_t)bh * 32 * 64 + t;
        float run = 0.f;
#pragma unroll
        for (int c = 0; c < 32; ++c) {
            float cur = Zc[base + (size_t)c * 64];
            Zc[base + (size_t)c * 64] = run;
            run += cur;
        }
    }
}

// ---------------------------------------------------------------------------
// Per (head,chunk): P = tril(Q K^T); den = rowsum(P)+Q.z_pre;
// num = P@V + Q@S_pre; out = num/den written IN PLACE over the Q plane.
// (Safe: each block reads only its own 128 Q rows; all Q reads precede the
//  post-barrier epilogue writes; no cross-block Q sharing.)
// ---------------------------------------------------------------------------
__global__ __launch_bounds__(256, 1) void attn_out_k(
    const u16* Qh, const u16* __restrict__ Kh,
    const u16* __restrict__ Vh, const u16* __restrict__ Sp,
    const float* __restrict__ Zp, u16* Qw)
{
    __shared__ __align__(16) u16 vtSh[64 * 136];   // V^T, +8 pad
    __shared__ __align__(16) u16 pSh[128 * 136];   // P,  +8 pad
    __shared__ float psum[128];
    __shared__ float qzs[128];
    int t = threadIdx.x, lane = t & 63, w = t >> 6;
    int q = lane >> 4, ln = lane & 15;
    int bhc = blockIdx.x, bh = bhc >> 5, ch = bhc & 31;
    const u16* Qb = Qh + ((size_t)bh * SEQ + (size_t)ch * CHUNK) * HD;
    const u16* Kb = Kh + ((size_t)bh * SEQ + (size_t)ch * CHUNK) * HD;
    const u16* Vb = Vh + ((size_t)bh * SEQ + (size_t)ch * CHUNK) * HD;
    const u16* Spb = Sp + (size_t)bhc * HD * HD;
    const float* Zpb = Zp + (size_t)bhc * HD;

    // stage V^T
#pragma unroll
    for (int i = 0; i < 4; ++i) {
        int g = i * 256 + t;
        int k = g >> 3, e0 = (g & 7) * 8;
        bf16x8 vv = *(const bf16x8*)&Vb[(size_t)k * HD + e0];
#pragma unroll
        for (int j = 0; j < 8; ++j) vtSh[(e0 + j) * 136 + k] = (u16)vv[j];
    }

    // GEMM1: scores = Q K^T, fragments straight from global
    int wm = (w & 1) * 64, wn = (w >> 1) * 64;
    bf16x8 afr[2][4];  // kept for Q@S_pre later
#pragma unroll
    for (int ks = 0; ks < 2; ++ks)
#pragma unroll
        for (int tm = 0; tm < 4; ++tm) {
            int m = wm + tm * 16 + ln;
            afr[ks][tm] = *(const bf16x8*)&Qb[(size_t)m * HD + ks * 32 + q * 8];
        }
    floatx4 acc[4][4] = {};
#pragma unroll
    for (int ks = 0; ks < 2; ++ks) {
        bf16x8 bfr[4];
#pragma unroll
        for (int tn = 0; tn < 4; ++tn) {
            int n = wn + tn * 16 + ln;
            bfr[tn] = *(const bf16x8*)&Kb[(size_t)n * HD + ks * 32 + q * 8];
        }
#pragma unroll
        for (int tm = 0; tm < 4; ++tm)
#pragma unroll
            for (int tn = 0; tn < 4; ++tn)
                acc[tm][tn] = __builtin_amdgcn_mfma_f32_16x16x32_bf16(
                    afr[ks][tm], bfr[tn], acc[tm][tn], 0, 0, 0);
    }
    // mask + write P
#pragma unroll
    for (int tm = 0; tm < 4; ++tm) {
        int rb = wm + tm * 16 + q * 4;
#pragma unroll
        for (int tn = 0; tn < 4; ++tn) {
            int cc = wn + tn * 16 + ln;
#pragma unroll
            for (int r = 0; r < 4; ++r) {
                float v = (cc <= rb + r) ? acc[tm][tn][r] : 0.f;
                pSh[(rb + r) * 136 + cc] = f2bf(v);
            }
        }
    }
    __syncthreads();
    // den parts
    if (t < 128) {
        const u16* prow = &pSh[t * 136];
        float s = 0.f;
#pragma unroll
        for (int i = 0; i < 16; ++i) {
            bf16x8 pv = *(const bf16x8*)&prow[i * 8];
#pragma unroll
            for (int j = 0; j < 8; ++j) s += bf2f((u16)pv[j]);
        }
        psum[t] = s;
    } else {
        int row = t - 128;
        float s = 0.f;
#pragma unroll
        for (int i = 0; i < 8; ++i) {
            bf16x8 qv = *(const bf16x8*)&Qb[(size_t)row * HD + i * 8];
#pragma unroll
            for (int j = 0; j < 8; ++j) s += bf2f((u16)qv[j]) * Zpb[i * 8 + j];
        }
        qzs[row] = s;
    }
    __syncthreads();

    // GEMM2: num = P @ V (K=128) + Q @ S_pre (K=64)
    int wn2 = (w >> 1) * 32;
    floatx4 acc2[4][2] = {};
#pragma unroll
    for (int ks = 0; ks < 4; ++ks) {
        bf16x8 ap[4], bv[2];
#pragma unroll
        for (int tm = 0; tm < 4; ++tm) {
            int m = wm + tm * 16 + ln;
            ap[tm] = *(const bf16x8*)&pSh[m * 136 + ks * 32 + q * 8];
        }
#pragma unroll
        for (int tn = 0; tn < 2; ++tn) {
            int n = wn2 + tn * 16 + ln;
            bv[tn] = *(const bf16x8*)&vtSh[n * 136 + ks * 32 + q * 8];
        }
#pragma unroll
        for (int tm = 0; tm < 4; ++tm)
#pragma unroll
            for (int tn = 0; tn < 2; ++tn)
                acc2[tm][tn] = __builtin_amdgcn_mfma_f32_16x16x32_bf16(
                    ap[tm], bv[tn], acc2[tm][tn], 0, 0, 0);
    }
#pragma unroll
    for (int ks = 0; ks < 2; ++ks) {
        bf16x8 bs[2];
#pragma unroll
        for (int tn = 0; tn < 2; ++tn) {
            int n = wn2 + tn * 16 + ln;
#pragma unroll
            for (int j = 0; j < 8; ++j)
                bs[tn][j] = (short)Spb[(size_t)(ks * 32 + q * 8 + j) * HD + n];
        }
#pragma unroll
        for (int tm = 0; tm < 4; ++tm)
#pragma unroll
            for (int tn = 0; tn < 2; ++tn)
                acc2[tm][tn] = __builtin_amdgcn_mfma_f32_16x16x32_bf16(
                    afr[ks][tm], bs[tn], acc2[tm][tn], 0, 0, 0);
    }
    // epilogue: divide, write in place over Q plane (head-major)
#pragma unroll
    for (int tm = 0; tm < 4; ++tm) {
        int rb = wm + tm * 16 + q * 4;
#pragma unroll
        for (int r = 0; r < 4; ++r) {
            int mrow = rb + r;
            float inv = 1.0f / fmaxf(psum[mrow] + qzs[mrow], 1e-20f);
            size_t orow = ((size_t)bh * SEQ + (size_t)ch * CHUNK + mrow) * HD;
#pragma unroll
            for (int tn = 0; tn < 2; ++tn) {
                int e = wn2 + tn * 16 + ln;
                Qw[orow + e] = f2bf(acc2[tm][tn][r] * inv);
            }
        }
    }
}

extern "C" void kernel_launch(void* const* d_in, const int* in_sizes, int n_in,
                              void* d_out, int out_size, void* d_ws, size_t ws_size,
                              hipStream_t stream) {
    const float* x  = (const float*)d_in[0];
    const float* Wq = (const float*)d_in[1];
    const float* bq = (const float*)d_in[2];
    const float* Wk = (const float*)d_in[3];
    const float* bk = (const float*)d_in[4];
    const float* Wv = (const float*)d_in[5];
    const float* bv = (const float*)d_in[6];
    const float* Wo = (const float*)d_in[7];
    const float* bo = (const float*)d_in[8];
    float* out = (float*)d_out;

    // per-batch ws: 3 bf16 planes (8.39 MB) + Sc bf16 (4.19 MB) + Zc f32
    const size_t PLANE = (size_t)NH * SEQ * HD;          // elements per batch plane
    const size_t PER_BATCH = 3 * PLANE * 2 + (size_t)NH * 32 * 4096 * 2
                           + (size_t)NH * 32 * HD * 4;   // = 29,491,200 B
    // Diagnostic guard: ws too small -> do nothing -> finite absmax 3.5156.
    if (ws_size < PER_BATCH) return;
    int nb = (ws_size >= 4 * PER_BATCH) ? 4 : (ws_size >= 2 * PER_BATCH) ? 2 : 1;

    for (int b0 = 0; b0 < 4; b0 += nb) {
        char* p = (char*)d_ws;
        u16* Qh = (u16*)p;  p += (size_t)nb * PLANE * 2;
        u16* Kh = (u16*)p;  p += (size_t)nb * PLANE * 2;
        u16* Vh = (u16*)p;  p += (size_t)nb * PLANE * 2;
        u16* Sc = (u16*)p;  p += (size_t)nb * NH * 32 * 4096 * 2;
        float* Zc = (float*)p;
        const float* xb = x + (size_t)b0 * SEQ * DM;

        dim3 g(nb * 32, 8), b(256);
        gemm_k<0><<<g, b, 0, stream>>>(xb, Wq, bq, Qh);
        gemm_k<0><<<g, b, 0, stream>>>(xb, Wk, bk, Kh);
        gemm_k<1><<<g, b, 0, stream>>>(xb, Wv, bv, Vh);
        chunk_stats_k<<<dim3(nb * 512), b, 0, stream>>>(Kh, Vh, Sc, Zc);
        prefix_k<<<dim3(nb * 16, 33), dim3(128), 0, stream>>>(Sc, Zc);
        attn_out_k<<<dim3(nb * 512), b, 0, stream>>>(Qh, Kh, Vh, Sc, Zc, Qh);
        gemm_k<2><<<g, b, 0, stream>>>(Qh, Wo, bo, out + (size_t)b0 * SEQ * DM);
    }
}

// Round 5
// 394.310 us; speedup vs baseline: 1.3142x; 1.3142x over previous
//
#include <hip/hip_runtime.h>
#include <hip/hip_bf16.h>

typedef __attribute__((ext_vector_type(8))) short bf16x8;
typedef __attribute__((ext_vector_type(4))) short bf16x4;
typedef __attribute__((ext_vector_type(4))) float floatx4;
typedef unsigned short u16;
typedef unsigned int u32;

#define DM 1024
#define SEQ 4096
#define NH 16
#define HD 64
#define CHUNK 128

__device__ __forceinline__ float bf2f(u16 x) {
    u32 u = ((u32)x) << 16;
    return __builtin_bit_cast(float, u);
}
__device__ __forceinline__ u16 f2bf(float f) {
    u32 u = __builtin_bit_cast(u32, f);
    u32 r = u + 0x7FFF + ((u >> 16) & 1);
    return (u16)(r >> 16);
}
__device__ __forceinline__ bf16x8 cvt8(const float* p) {
    floatx4 a = *(const floatx4*)p;
    floatx4 b = *(const floatx4*)(p + 4);
    bf16x8 r;
    r[0] = (short)f2bf(a[0]); r[1] = (short)f2bf(a[1]);
    r[2] = (short)f2bf(a[2]); r[3] = (short)f2bf(a[3]);
    r[4] = (short)f2bf(b[0]); r[5] = (short)f2bf(b[1]);
    r[6] = (short)f2bf(b[2]); r[7] = (short)f2bf(b[3]);
    return r;
}
// async global->LDS, 16B/lane; LDS dest = wave-uniform base + lane*16 (m97).
__device__ __forceinline__ void async_copy16(const u16* gsrc, u16* ldst) {
    __builtin_amdgcn_global_load_lds(
        (const __attribute__((address_space(1))) void*)gsrc,
        (__attribute__((address_space(3))) void*)ldst, 16, 0, 0);
}

// ---------------------------------------------------------------------------
// f32 -> bf16 pre-conversion. Weights: Wq,Wk,Wv stacked into Wqkv[3072][1024],
// Wo into Wob. x slices converted per batch group.
// ---------------------------------------------------------------------------
__global__ void cvt_w_k(const float* __restrict__ Wq, const float* __restrict__ Wk,
                        const float* __restrict__ Wv, const float* __restrict__ Wo,
                        u16* __restrict__ Wqkv, u16* __restrict__ Wob)
{
    int g = blockIdx.x * 256 + threadIdx.x;   // granule id, 0..524287
    int w = g >> 17;                          // 0..3 (whole blocks uniform)
    int off = g & 131071;
    const float* src = (w == 0) ? Wq : (w == 1) ? Wk : (w == 2) ? Wv : Wo;
    u16* dst = (w < 3) ? (Wqkv + ((size_t)w << 20)) : Wob;
    *(bf16x8*)&dst[(size_t)off * 8] = cvt8(src + (size_t)off * 8);
}

__global__ void cvt_x_k(const float* __restrict__ xs, u16* __restrict__ xb)
{
    size_t g = (size_t)blockIdx.x * 256 + threadIdx.x;
    *(bf16x8*)&xb[g * 8] = cvt8(xs + g * 8);
}

// ---------------------------------------------------------------------------
// Fused QKV GEMM: [M,1024] bf16 @ Wqkv[3072,1024]^T + bias -> phi (Q,K) /
// plain (V) head-major bf16 planes. 128x128 tile, BK=64, 4 waves,
// mfma 16x16x32 bf16, global_load_lds w=16 staging, XOR-granule swizzle
// applied on the GLOBAL address (DMA order must stay lane-linear).
// grid: (24 n-tiles, M/128 m-tiles)
// ---------------------------------------------------------------------------
__global__ __launch_bounds__(256, 2) void qkv_gemm_k(
    const u16* __restrict__ xb, const u16* __restrict__ Wqkv,
    const float* __restrict__ bq, const float* __restrict__ bk,
    const float* __restrict__ bv,
    u16* __restrict__ Qh, u16* __restrict__ Kh, u16* __restrict__ Vh)
{
    __shared__ __align__(16) u16 aSh[128 * 64];
    __shared__ __align__(16) u16 bSh[128 * 64];
    int t = threadIdx.x, lane = t & 63, w = t >> 6;
    int q = lane >> 4, ln = lane & 15;
    int wm = (w & 1) * 64, wn = (w >> 1) * 64;
    int n0 = blockIdx.x * 128, m0 = blockIdx.y * 128;
    int wgr = t & 192;  // wave-uniform granule base within each 256-granule round
    floatx4 acc[4][4] = {};

    for (int k0 = 0; k0 < DM; k0 += 64) {
#pragma unroll
        for (int i = 0; i < 4; ++i) {
            int gi = i * 256 + t;
            int r = gi >> 3;
            int c = (gi & 7) ^ (r & 7);
            async_copy16(xb + (size_t)(m0 + r) * DM + k0 + c * 8,
                         aSh + (size_t)(i * 256 + wgr) * 8);
            async_copy16(Wqkv + (size_t)(n0 + r) * DM + k0 + c * 8,
                         bSh + (size_t)(i * 256 + wgr) * 8);
        }
        __builtin_amdgcn_s_waitcnt(0);
        __syncthreads();
#pragma unroll
        for (int ks = 0; ks < 2; ++ks) {
            int cg = ks * 4 + q;
            bf16x8 af[4], bfv[4];
#pragma unroll
            for (int tm = 0; tm < 4; ++tm) {
                int m = wm + tm * 16 + ln;
                af[tm] = *(const bf16x8*)&aSh[(m * 8 + (cg ^ (m & 7))) * 8];
            }
#pragma unroll
            for (int tn = 0; tn < 4; ++tn) {
                int n = wn + tn * 16 + ln;
                bfv[tn] = *(const bf16x8*)&bSh[(n * 8 + (cg ^ (n & 7))) * 8];
            }
#pragma unroll
            for (int tm = 0; tm < 4; ++tm)
#pragma unroll
                for (int tn = 0; tn < 4; ++tn)
                    acc[tm][tn] = __builtin_amdgcn_mfma_f32_16x16x32_bf16(
                        af[tm], bfv[tn], acc[tm][tn], 0, 0, 0);
        }
        __syncthreads();  // all reads done before next DMA overwrites LDS
    }
    // Epilogue. C/D: col=lane&15, row=quad*4+reg.
#pragma unroll
    for (int tn = 0; tn < 4; ++tn) {
        int gn = n0 + wn + tn * 16 + ln;       // 0..3071
        int proj = gn >> 10, col = gn & 1023;  // proj uniform per tn
        float bb = ((proj == 0) ? bq : (proj == 1) ? bk : bv)[col];
        u16* plane = (proj == 0) ? Qh : (proj == 1) ? Kh : Vh;
        int head = col >> 6, dl = col & 63;
#pragma unroll
        for (int tm = 0; tm < 4; ++tm) {
            int gmb = m0 + wm + tm * 16 + q * 4;
#pragma unroll
            for (int r = 0; r < 4; ++r) {
                int gm = gmb + r;
                float v = acc[tm][tn][r] + bb;
                if (proj < 2) v = (v > 0.f) ? (v + 1.f) : __expf(v);
                plane[(((size_t)(gm >> 12) * NH + head) * SEQ + (gm & 4095)) * HD + dl]
                    = f2bf(v);
            }
        }
    }
}

// ---------------------------------------------------------------------------
// Output GEMM: A = head-major bf16 plane (attn out), Wob bf16, out f32.
// grid: (8 n-tiles, M/128)
// ---------------------------------------------------------------------------
__global__ __launch_bounds__(256, 2) void out_gemm_k(
    const u16* __restrict__ Ah, const u16* __restrict__ Wob,
    const float* __restrict__ bo, float* __restrict__ out)
{
    __shared__ __align__(16) u16 aSh[128 * 64];
    __shared__ __align__(16) u16 bSh[128 * 64];
    int t = threadIdx.x, lane = t & 63, w = t >> 6;
    int q = lane >> 4, ln = lane & 15;
    int wm = (w & 1) * 64, wn = (w >> 1) * 64;
    int n0 = blockIdx.x * 128, m0 = blockIdx.y * 128;
    int wgr = t & 192;
    floatx4 acc[4][4] = {};

    for (int k0 = 0; k0 < DM; k0 += 64) {
#pragma unroll
        for (int i = 0; i < 4; ++i) {
            int gi = i * 256 + t;
            int r = gi >> 3;
            int c = (gi & 7) ^ (r & 7);
            int rr = m0 + r;  // plane: ((bl*16+head)*4096+s)*64+dl ; head=k0>>6
            async_copy16(Ah + (((size_t)((rr >> 12) * NH + (k0 >> 6))) << 18)
                            + (size_t)((rr & 4095) << 6) + (size_t)(c * 8),
                         aSh + (size_t)(i * 256 + wgr) * 8);
            async_copy16(Wob + (size_t)(n0 + r) * DM + k0 + c * 8,
                         bSh + (size_t)(i * 256 + wgr) * 8);
        }
        __builtin_amdgcn_s_waitcnt(0);
        __syncthreads();
#pragma unroll
        for (int ks = 0; ks < 2; ++ks) {
            int cg = ks * 4 + q;
            bf16x8 af[4], bfv[4];
#pragma unroll
            for (int tm = 0; tm < 4; ++tm) {
                int m = wm + tm * 16 + ln;
                af[tm] = *(const bf16x8*)&aSh[(m * 8 + (cg ^ (m & 7))) * 8];
            }
#pragma unroll
            for (int tn = 0; tn < 4; ++tn) {
                int n = wn + tn * 16 + ln;
                bfv[tn] = *(const bf16x8*)&bSh[(n * 8 + (cg ^ (n & 7))) * 8];
            }
#pragma unroll
            for (int tm = 0; tm < 4; ++tm)
#pragma unroll
                for (int tn = 0; tn < 4; ++tn)
                    acc[tm][tn] = __builtin_amdgcn_mfma_f32_16x16x32_bf16(
                        af[tm], bfv[tn], acc[tm][tn], 0, 0, 0);
        }
        __syncthreads();
    }
#pragma unroll
    for (int tn = 0; tn < 4; ++tn) {
        int gn = n0 + wn + tn * 16 + ln;
        float bb = bo[gn];
#pragma unroll
        for (int tm = 0; tm < 4; ++tm) {
            int gmb = m0 + wm + tm * 16 + q * 4;
#pragma unroll
            for (int r = 0; r < 4; ++r)
                out[(size_t)(gmb + r) * DM + gn] = acc[tm][tn][r] + bb;
        }
    }
}

// ---------------------------------------------------------------------------
// Per (head,chunk): Sc[d][e] = sum_r K[r][d]*V[r][e] (bf16); Zc[d]=sum_r K[r][d]
// ---------------------------------------------------------------------------
__global__ __launch_bounds__(256, 1) void chunk_stats_k(
    const u16* __restrict__ Kh, const u16* __restrict__ Vh,
    u16* __restrict__ Sc, float* __restrict__ Zc)
{
    __shared__ __align__(16) u16 kSh[128 * 64];
    __shared__ __align__(16) u16 vSh[128 * 64];
    int t = threadIdx.x;
    int bhc = blockIdx.x;
    const u16* Kb = Kh + ((size_t)(bhc >> 5) * SEQ + (size_t)(bhc & 31) * CHUNK) * HD;
    const u16* Vb = Vh + ((size_t)(bhc >> 5) * SEQ + (size_t)(bhc & 31) * CHUNK) * HD;
#pragma unroll
    for (int i = 0; i < 4; ++i) {
        int g = i * 256 + t;
        *(bf16x8*)&kSh[g * 8] = *(const bf16x8*)&Kb[(size_t)g * 8];
        *(bf16x8*)&vSh[g * 8] = *(const bf16x8*)&Vb[(size_t)g * 8];
    }
    __syncthreads();
    int eg = t & 15, dg = t >> 4;
    float acc[4][4] = {};
#pragma unroll 4
    for (int r = 0; r < 128; ++r) {
        bf16x4 kq = *(const bf16x4*)&kSh[r * 64 + dg * 4];
        bf16x4 vq = *(const bf16x4*)&vSh[r * 64 + eg * 4];
        float kf[4], vf[4];
#pragma unroll
        for (int i = 0; i < 4; ++i) { kf[i] = bf2f((u16)kq[i]); vf[i] = bf2f((u16)vq[i]); }
#pragma unroll
        for (int a = 0; a < 4; ++a)
#pragma unroll
            for (int b = 0; b < 4; ++b) acc[a][b] += kf[a] * vf[b];
    }
    u16* So = Sc + (size_t)bhc * HD * HD;
#pragma unroll
    for (int a = 0; a < 4; ++a) {
        bf16x4 sv;
#pragma unroll
        for (int b = 0; b < 4; ++b) sv[b] = (short)f2bf(acc[a][b]);
        *(bf16x4*)&So[(dg * 4 + a) * HD + eg * 4] = sv;
    }
    if (t < 64) {
        float z = 0.f;
        for (int r = 0; r < 128; ++r) z += bf2f(kSh[r * 64 + t]);
        Zc[(size_t)bhc * HD + t] = z;
    }
}

// ---------------------------------------------------------------------------
// Exclusive prefix over 32 chunks (per bh). grid (nbh, 33).
// ---------------------------------------------------------------------------
__global__ void prefix_k(u16* __restrict__ Sc, float* __restrict__ Zc)
{
    int bh = blockIdx.x, y = blockIdx.y, t = threadIdx.x;
    if (y < 32) {
        size_t base = (size_t)bh * 32 * 4096 + y * 128 + t;
        float run = 0.f;
#pragma unroll
        for (int c = 0; c < 32; ++c) {
            float cur = bf2f(Sc[base + (size_t)c * 4096]);
            Sc[base + (size_t)c * 4096] = f2bf(run);
            run += cur;
        }
    } else if (t < 64) {
        size_t base = (size_t)bh * 32 * 64 + t;
        float run = 0.f;
#pragma unroll
        for (int c = 0; c < 32; ++c) {
            float cur = Zc[base + (size_t)c * 64];
            Zc[base + (size_t)c * 64] = run;
            run += cur;
        }
    }
}

// ---------------------------------------------------------------------------
// Per (head,chunk): P = tril(Q K^T); den = rowsum(P)+Q.z_pre;
// num = P@V + Q@S_pre; out = num/den written IN PLACE over the Q plane.
// ---------------------------------------------------------------------------
__global__ __launch_bounds__(256, 1) void attn_out_k(
    const u16* Qh, const u16* __restrict__ Kh,
    const u16* __restrict__ Vh, const u16* __restrict__ Sp,
    const float* __restrict__ Zp, u16* Qw)
{
    __shared__ __align__(16) u16 vtSh[64 * 136];   // V^T, +8 pad
    __shared__ __align__(16) u16 pSh[128 * 136];   // P,  +8 pad
    __shared__ float psum[128];
    __shared__ float qzs[128];
    int t = threadIdx.x, lane = t & 63, w = t >> 6;
    int q = lane >> 4, ln = lane & 15;
    int bhc = blockIdx.x, bh = bhc >> 5, ch = bhc & 31;
    const u16* Qb = Qh + ((size_t)bh * SEQ + (size_t)ch * CHUNK) * HD;
    const u16* Kb = Kh + ((size_t)bh * SEQ + (size_t)ch * CHUNK) * HD;
    const u16* Vb = Vh + ((size_t)bh * SEQ + (size_t)ch * CHUNK) * HD;
    const u16* Spb = Sp + (size_t)bhc * HD * HD;
    const float* Zpb = Zp + (size_t)bhc * HD;

    // stage V^T
#pragma unroll
    for (int i = 0; i < 4; ++i) {
        int g = i * 256 + t;
        int k = g >> 3, e0 = (g & 7) * 8;
        bf16x8 vv = *(const bf16x8*)&Vb[(size_t)k * HD + e0];
#pragma unroll
        for (int j = 0; j < 8; ++j) vtSh[(e0 + j) * 136 + k] = (u16)vv[j];
    }

    // GEMM1: scores = Q K^T, fragments straight from global
    int wm = (w & 1) * 64, wn = (w >> 1) * 64;
    bf16x8 afr[2][4];  // kept for Q@S_pre later
#pragma unroll
    for (int ks = 0; ks < 2; ++ks)
#pragma unroll
        for (int tm = 0; tm < 4; ++tm) {
            int m = wm + tm * 16 + ln;
            afr[ks][tm] = *(const bf16x8*)&Qb[(size_t)m * HD + ks * 32 + q * 8];
        }
    floatx4 acc[4][4] = {};
#pragma unroll
    for (int ks = 0; ks < 2; ++ks) {
        bf16x8 bfr[4];
#pragma unroll
        for (int tn = 0; tn < 4; ++tn) {
            int n = wn + tn * 16 + ln;
            bfr[tn] = *(const bf16x8*)&Kb[(size_t)n * HD + ks * 32 + q * 8];
        }
#pragma unroll
        for (int tm = 0; tm < 4; ++tm)
#pragma unroll
            for (int tn = 0; tn < 4; ++tn)
                acc[tm][tn] = __builtin_amdgcn_mfma_f32_16x16x32_bf16(
                    afr[ks][tm], bfr[tn], acc[tm][tn], 0, 0, 0);
    }
    // mask + write P
#pragma unroll
    for (int tm = 0; tm < 4; ++tm) {
        int rb = wm + tm * 16 + q * 4;
#pragma unroll
        for (int tn = 0; tn < 4; ++tn) {
            int cc = wn + tn * 16 + ln;
#pragma unroll
            for (int r = 0; r < 4; ++r) {
                float v = (cc <= rb + r) ? acc[tm][tn][r] : 0.f;
                pSh[(rb + r) * 136 + cc] = f2bf(v);
            }
        }
    }
    __syncthreads();
    // den parts
    if (t < 128) {
        const u16* prow = &pSh[t * 136];
        float s = 0.f;
#pragma unroll
        for (int i = 0; i < 16; ++i) {
            bf16x8 pv = *(const bf16x8*)&prow[i * 8];
#pragma unroll
            for (int j = 0; j < 8; ++j) s += bf2f((u16)pv[j]);
        }
        psum[t] = s;
    } else {
        int row = t - 128;
        float s = 0.f;
#pragma unroll
        for (int i = 0; i < 8; ++i) {
            bf16x8 qv = *(const bf16x8*)&Qb[(size_t)row * HD + i * 8];
#pragma unroll
            for (int j = 0; j < 8; ++j) s += bf2f((u16)qv[j]) * Zpb[i * 8 + j];
        }
        qzs[row] = s;
    }
    __syncthreads();

    // GEMM2: num = P @ V (K=128) + Q @ S_pre (K=64)
    int wn2 = (w >> 1) * 32;
    floatx4 acc2[4][2] = {};
#pragma unroll
    for (int ks = 0; ks < 4; ++ks) {
        bf16x8 ap[4], bv[2];
#pragma unroll
        for (int tm = 0; tm < 4; ++tm) {
            int m = wm + tm * 16 + ln;
            ap[tm] = *(const bf16x8*)&pSh[m * 136 + ks * 32 + q * 8];
        }
#pragma unroll
        for (int tn = 0; tn < 2; ++tn) {
            int n = wn2 + tn * 16 + ln;
            bv[tn] = *(const bf16x8*)&vtSh[n * 136 + ks * 32 + q * 8];
        }
#pragma unroll
        for (int tm = 0; tm < 4; ++tm)
#pragma unroll
            for (int tn = 0; tn < 2; ++tn)
                acc2[tm][tn] = __builtin_amdgcn_mfma_f32_16x16x32_bf16(
                    ap[tm], bv[tn], acc2[tm][tn], 0, 0, 0);
    }
#pragma unroll
    for (int ks = 0; ks < 2; ++ks) {
        bf16x8 bs[2];
#pragma unroll
        for (int tn = 0; tn < 2; ++tn) {
            int n = wn2 + tn * 16 + ln;
#pragma unroll
            for (int j = 0; j < 8; ++j)
                bs[tn][j] = (short)Spb[(size_t)(ks * 32 + q * 8 + j) * HD + n];
        }
#pragma unroll
        for (int tm = 0; tm < 4; ++tm)
#pragma unroll
            for (int tn = 0; tn < 2; ++tn)
                acc2[tm][tn] = __builtin_amdgcn_mfma_f32_16x16x32_bf16(
                    afr[ks][tm], bs[tn], acc2[tm][tn], 0, 0, 0);
    }
    // epilogue: divide, write in place over Q plane (head-major)
#pragma unroll
    for (int tm = 0; tm < 4; ++tm) {
        int rb = wm + tm * 16 + q * 4;
#pragma unroll
        for (int r = 0; r < 4; ++r) {
            int mrow = rb + r;
            float inv = 1.0f / fmaxf(psum[mrow] + qzs[mrow], 1e-20f);
            size_t orow = ((size_t)bh * SEQ + (size_t)ch * CHUNK + mrow) * HD;
#pragma unroll
            for (int tn = 0; tn < 2; ++tn) {
                int e = wn2 + tn * 16 + ln;
                Qw[orow + e] = f2bf(acc2[tm][tn][r] * inv);
            }
        }
    }
}

extern "C" void kernel_launch(void* const* d_in, const int* in_sizes, int n_in,
                              void* d_out, int out_size, void* d_ws, size_t ws_size,
                              hipStream_t stream) {
    const float* x  = (const float*)d_in[0];
    const float* Wq = (const float*)d_in[1];
    const float* bq = (const float*)d_in[2];
    const float* Wk = (const float*)d_in[3];
    const float* bk = (const float*)d_in[4];
    const float* Wv = (const float*)d_in[5];
    const float* bv = (const float*)d_in[6];
    const float* Wo = (const float*)d_in[7];
    const float* bo = (const float*)d_in[8];
    float* out = (float*)d_out;

    // ws: fixed = Wqkv bf16 (6.29 MB) + Wob bf16 (2.10 MB);
    // per batch = xb 8.39 + Q/K/V planes 25.17 + Sc 4.19 + Zc 0.13 = 37.9 MB
    const size_t PLANE = (size_t)NH * SEQ * HD;  // elems per batch plane
    const size_t FIXED = (3 * (size_t)DM * DM + (size_t)DM * DM) * 2;
    const size_t PER_BATCH = 4 * PLANE * 2 + (size_t)NH * 32 * 4096 * 2
                           + (size_t)NH * 32 * HD * 4;
    if (ws_size < FIXED + PER_BATCH) return;  // diagnostic: finite absmax 3.5156
    int nb = (ws_size >= FIXED + 4 * PER_BATCH) ? 4
           : (ws_size >= FIXED + 2 * PER_BATCH) ? 2 : 1;

    char* p0 = (char*)d_ws;
    u16* Wqkv = (u16*)p0;                       p0 += 3 * (size_t)DM * DM * 2;
    u16* Wob  = (u16*)p0;                       p0 += (size_t)DM * DM * 2;

    cvt_w_k<<<dim3(2048), dim3(256), 0, stream>>>(Wq, Wk, Wv, Wo, Wqkv, Wob);

    for (int b0 = 0; b0 < 4; b0 += nb) {
        char* p = p0;
        u16* xb = (u16*)p;  p += (size_t)nb * PLANE * 2;
        u16* Qh = (u16*)p;  p += (size_t)nb * PLANE * 2;
        u16* Kh = (u16*)p;  p += (size_t)nb * PLANE * 2;
        u16* Vh = (u16*)p;  p += (size_t)nb * PLANE * 2;
        u16* Sc = (u16*)p;  p += (size_t)nb * NH * 32 * 4096 * 2;
        float* Zc = (float*)p;
        const float* xs = x + (size_t)b0 * SEQ * DM;

        cvt_x_k<<<dim3(nb * 2048), dim3(256), 0, stream>>>(xs, xb);
        qkv_gemm_k<<<dim3(24, nb * 32), dim3(256), 0, stream>>>(
            xb, Wqkv, bq, bk, bv, Qh, Kh, Vh);
        chunk_stats_k<<<dim3(nb * 512), dim3(256), 0, stream>>>(Kh, Vh, Sc, Zc);
        prefix_k<<<dim3(nb * 16, 33), dim3(128), 0, stream>>>(Sc, Zc);
        attn_out_k<<<dim3(nb * 512), dim3(256), 0, stream>>>(Qh, Kh, Vh, Sc, Zc, Qh);
        out_gemm_k<<<dim3(8, nb * 32), dim3(256), 0, stream>>>(
            Qh, Wob, bo, out + (size_t)b0 * SEQ * DM);
    }
}

// Round 7
// 391.871 us; speedup vs baseline: 1.3224x; 1.0062x over previous
//
#include <hip/hip_runtime.h>
#include <hip/hip_bf16.h>

typedef __attribute__((ext_vector_type(8))) short bf16x8;
typedef __attribute__((ext_vector_type(4))) short bf16x4;
typedef __attribute__((ext_vector_type(4))) float floatx4;
typedef unsigned short u16;
typedef unsigned int u32;

#define DM 1024
#define SEQ 4096
#define NH 16
#define HD 64
#define CHUNK 128

__device__ __forceinline__ float bf2f(u16 x) {
    u32 u = ((u32)x) << 16;
    return __builtin_bit_cast(float, u);
}
__device__ __forceinline__ u16 f2bf(float f) {
    u32 u = __builtin_bit_cast(u32, f);
    u32 r = u + 0x7FFF + ((u >> 16) & 1);
    return (u16)(r >> 16);
}
__device__ __forceinline__ bf16x8 cvt8(const float* p) {
    floatx4 a = *(const floatx4*)p;
    floatx4 b = *(const floatx4*)(p + 4);
    bf16x8 r;
    r[0] = (short)f2bf(a[0]); r[1] = (short)f2bf(a[1]);
    r[2] = (short)f2bf(a[2]); r[3] = (short)f2bf(a[3]);
    r[4] = (short)f2bf(b[0]); r[5] = (short)f2bf(b[1]);
    r[6] = (short)f2bf(b[2]); r[7] = (short)f2bf(b[3]);
    return r;
}
// async global->LDS, 16B/lane; LDS dest = wave-uniform base + lane*16 (m97).
__device__ __forceinline__ void async_copy16(const u16* gsrc, u16* ldst) {
    __builtin_amdgcn_global_load_lds(
        (const __attribute__((address_space(1))) void*)gsrc,
        (__attribute__((address_space(3))) void*)ldst, 16, 0, 0);
}

// ---------------------------------------------------------------------------
// f32 -> bf16 pre-conversion.
// ---------------------------------------------------------------------------
__global__ void cvt_w_k(const float* __restrict__ Wq, const float* __restrict__ Wk,
                        const float* __restrict__ Wv, const float* __restrict__ Wo,
                        u16* __restrict__ Wqkv, u16* __restrict__ Wob)
{
    int g = blockIdx.x * 256 + threadIdx.x;   // granule id, 0..524287
    int w = g >> 17;                          // 0..3 (whole blocks uniform)
    int off = g & 131071;
    const float* src = (w == 0) ? Wq : (w == 1) ? Wk : (w == 2) ? Wv : Wo;
    u16* dst = (w < 3) ? (Wqkv + ((size_t)w << 20)) : Wob;
    *(bf16x8*)&dst[(size_t)off * 8] = cvt8(src + (size_t)off * 8);
}

__global__ void cvt_x_k(const float* __restrict__ xs, u16* __restrict__ xb)
{
    size_t g = (size_t)blockIdx.x * 256 + threadIdx.x;
    *(bf16x8*)&xb[g * 8] = cvt8(xs + g * 8);
}

// ---------------------------------------------------------------------------
// Fused QKV GEMM: [M,1024] bf16 @ Wqkv[3072,1024]^T + bias -> phi (Q,K) /
// plain (V) head-major bf16 planes. 128x128 tile, BK=64, 4 waves,
// mfma 16x16x32 bf16, global_load_lds w=16 staging, XOR-granule swizzle.
// ---------------------------------------------------------------------------
__global__ __launch_bounds__(256, 2) void qkv_gemm_k(
    const u16* __restrict__ xb, const u16* __restrict__ Wqkv,
    const float* __restrict__ bq, const float* __restrict__ bk,
    const float* __restrict__ bv,
    u16* __restrict__ Qh, u16* __restrict__ Kh, u16* __restrict__ Vh)
{
    __shared__ __align__(16) u16 aSh[128 * 64];
    __shared__ __align__(16) u16 bSh[128 * 64];
    int t = threadIdx.x, lane = t & 63, w = t >> 6;
    int q = lane >> 4, ln = lane & 15;
    int wm = (w & 1) * 64, wn = (w >> 1) * 64;
    int n0 = blockIdx.x * 128, m0 = blockIdx.y * 128;
    int wgr = t & 192;
    floatx4 acc[4][4] = {};

    for (int k0 = 0; k0 < DM; k0 += 64) {
#pragma unroll
        for (int i = 0; i < 4; ++i) {
            int gi = i * 256 + t;
            int r = gi >> 3;
            int c = (gi & 7) ^ (r & 7);
            async_copy16(xb + (size_t)(m0 + r) * DM + k0 + c * 8,
                         aSh + (size_t)(i * 256 + wgr) * 8);
            async_copy16(Wqkv + (size_t)(n0 + r) * DM + k0 + c * 8,
                         bSh + (size_t)(i * 256 + wgr) * 8);
        }
        __builtin_amdgcn_s_waitcnt(0);
        __syncthreads();
#pragma unroll
        for (int ks = 0; ks < 2; ++ks) {
            int cg = ks * 4 + q;
            bf16x8 af[4], bfv[4];
#pragma unroll
            for (int tm = 0; tm < 4; ++tm) {
                int m = wm + tm * 16 + ln;
                af[tm] = *(const bf16x8*)&aSh[(m * 8 + (cg ^ (m & 7))) * 8];
            }
#pragma unroll
            for (int tn = 0; tn < 4; ++tn) {
                int n = wn + tn * 16 + ln;
                bfv[tn] = *(const bf16x8*)&bSh[(n * 8 + (cg ^ (n & 7))) * 8];
            }
#pragma unroll
            for (int tm = 0; tm < 4; ++tm)
#pragma unroll
                for (int tn = 0; tn < 4; ++tn)
                    acc[tm][tn] = __builtin_amdgcn_mfma_f32_16x16x32_bf16(
                        af[tm], bfv[tn], acc[tm][tn], 0, 0, 0);
        }
        __syncthreads();
    }
    // Epilogue. C/D: col=lane&15, row=quad*4+reg.
#pragma unroll
    for (int tn = 0; tn < 4; ++tn) {
        int gn = n0 + wn + tn * 16 + ln;       // 0..3071
        int proj = gn >> 10, col = gn & 1023;
        float bb = ((proj == 0) ? bq : (proj == 1) ? bk : bv)[col];
        u16* plane = (proj == 0) ? Qh : (proj == 1) ? Kh : Vh;
        int head = col >> 6, dl = col & 63;
#pragma unroll
        for (int tm = 0; tm < 4; ++tm) {
            int gmb = m0 + wm + tm * 16 + q * 4;
#pragma unroll
            for (int r = 0; r < 4; ++r) {
                int gm = gmb + r;
                float v = acc[tm][tn][r] + bb;
                if (proj < 2) v = (v > 0.f) ? (v + 1.f) : __expf(v);
                plane[(((size_t)(gm >> 12) * NH + head) * SEQ + (gm & 4095)) * HD + dl]
                    = f2bf(v);
            }
        }
    }
}

// ---------------------------------------------------------------------------
// Output GEMM: A = head-major bf16 plane (attn out), Wob bf16, out f32.
// ---------------------------------------------------------------------------
__global__ __launch_bounds__(256, 2) void out_gemm_k(
    const u16* __restrict__ Ah, const u16* __restrict__ Wob,
    const float* __restrict__ bo, float* __restrict__ out)
{
    __shared__ __align__(16) u16 aSh[128 * 64];
    __shared__ __align__(16) u16 bSh[128 * 64];
    int t = threadIdx.x, lane = t & 63, w = t >> 6;
    int q = lane >> 4, ln = lane & 15;
    int wm = (w & 1) * 64, wn = (w >> 1) * 64;
    int n0 = blockIdx.x * 128, m0 = blockIdx.y * 128;
    int wgr = t & 192;
    floatx4 acc[4][4] = {};

    for (int k0 = 0; k0 < DM; k0 += 64) {
#pragma unroll
        for (int i = 0; i < 4; ++i) {
            int gi = i * 256 + t;
            int r = gi >> 3;
            int c = (gi & 7) ^ (r & 7);
            int rr = m0 + r;  // plane: ((bl*16+head)*4096+s)*64+dl ; head=k0>>6
            async_copy16(Ah + (((size_t)((rr >> 12) * NH + (k0 >> 6))) << 18)
                            + (size_t)((rr & 4095) << 6) + (size_t)(c * 8),
                         aSh + (size_t)(i * 256 + wgr) * 8);
            async_copy16(Wob + (size_t)(n0 + r) * DM + k0 + c * 8,
                         bSh + (size_t)(i * 256 + wgr) * 8);
        }
        __builtin_amdgcn_s_waitcnt(0);
        __syncthreads();
#pragma unroll
        for (int ks = 0; ks < 2; ++ks) {
            int cg = ks * 4 + q;
            bf16x8 af[4], bfv[4];
#pragma unroll
            for (int tm = 0; tm < 4; ++tm) {
                int m = wm + tm * 16 + ln;
                af[tm] = *(const bf16x8*)&aSh[(m * 8 + (cg ^ (m & 7))) * 8];
            }
#pragma unroll
            for (int tn = 0; tn < 4; ++tn) {
                int n = wn + tn * 16 + ln;
                bfv[tn] = *(const bf16x8*)&bSh[(n * 8 + (cg ^ (n & 7))) * 8];
            }
#pragma unroll
            for (int tm = 0; tm < 4; ++tm)
#pragma unroll
                for (int tn = 0; tn < 4; ++tn)
                    acc[tm][tn] = __builtin_amdgcn_mfma_f32_16x16x32_bf16(
                        af[tm], bfv[tn], acc[tm][tn], 0, 0, 0);
        }
        __syncthreads();
    }
#pragma unroll
    for (int tn = 0; tn < 4; ++tn) {
        int gn = n0 + wn + tn * 16 + ln;
        float bb = bo[gn];
#pragma unroll
        for (int tm = 0; tm < 4; ++tm) {
            int gmb = m0 + wm + tm * 16 + q * 4;
#pragma unroll
            for (int r = 0; r < 4; ++r)
                out[(size_t)(gmb + r) * DM + gn] = acc[tm][tn][r] + bb;
        }
    }
}

// ---------------------------------------------------------------------------
// Per (head,chunk): St[e][d] = sum_r V[r][e]*K[r][d]  (S TRANSPOSED, bf16);
// Zc[d] = sum_r K[r][d].  S^T layout makes attn's Q@S B-frags vector loads.
// ---------------------------------------------------------------------------
__global__ __launch_bounds__(256, 1) void chunk_stats_k(
    const u16* __restrict__ Kh, const u16* __restrict__ Vh,
    u16* __restrict__ Sc, float* __restrict__ Zc)
{
    __shared__ __align__(16) u16 kSh[128 * 64];
    __shared__ __align__(16) u16 vSh[128 * 64];
    int t = threadIdx.x;
    int bhc = blockIdx.x;
    const u16* Kb = Kh + ((size_t)(bhc >> 5) * SEQ + (size_t)(bhc & 31) * CHUNK) * HD;
    const u16* Vb = Vh + ((size_t)(bhc >> 5) * SEQ + (size_t)(bhc & 31) * CHUNK) * HD;
#pragma unroll
    for (int i = 0; i < 4; ++i) {
        int g = i * 256 + t;
        *(bf16x8*)&kSh[g * 8] = *(const bf16x8*)&Kb[(size_t)g * 8];
        *(bf16x8*)&vSh[g * 8] = *(const bf16x8*)&Vb[(size_t)g * 8];
    }
    __syncthreads();
    int tD = t & 15, tE = t >> 4;   // d-group, e-group
    float acc[4][4] = {};
#pragma unroll 4
    for (int r = 0; r < 128; ++r) {
        bf16x4 vq = *(const bf16x4*)&vSh[r * 64 + tE * 4];
        bf16x4 kq = *(const bf16x4*)&kSh[r * 64 + tD * 4];
        float vf[4], kf[4];
#pragma unroll
        for (int i = 0; i < 4; ++i) { vf[i] = bf2f((u16)vq[i]); kf[i] = bf2f((u16)kq[i]); }
#pragma unroll
        for (int a = 0; a < 4; ++a)
#pragma unroll
            for (int b = 0; b < 4; ++b) acc[a][b] += vf[a] * kf[b];
    }
    u16* So = Sc + (size_t)bhc * HD * HD;
#pragma unroll
    for (int a = 0; a < 4; ++a) {
        bf16x4 sv;
#pragma unroll
        for (int b = 0; b < 4; ++b) sv[b] = (short)f2bf(acc[a][b]);
        *(bf16x4*)&So[(tE * 4 + a) * HD + tD * 4] = sv;  // S^T: e row, d cols
    }
    if (t < 64) {
        float z = 0.f;
        for (int r = 0; r < 128; ++r) z += bf2f(kSh[r * 64 + t]);
        Zc[(size_t)bhc * HD + t] = z;
    }
}

// ---------------------------------------------------------------------------
// Exclusive prefix over 32 chunks (per bh). Elementwise -> layout-agnostic.
// ---------------------------------------------------------------------------
__global__ void prefix_k(u16* __restrict__ Sc, float* __restrict__ Zc)
{
    int bh = blockIdx.x, y = blockIdx.y, t = threadIdx.x;
    if (y < 32) {
        size_t base = (size_t)bh * 32 * 4096 + y * 128 + t;
        float run = 0.f;
#pragma unroll
        for (int c = 0; c < 32; ++c) {
            float cur = bf2f(Sc[base + (size_t)c * 4096]);
            Sc[base + (size_t)c * 4096] = f2bf(run);
            run += cur;
        }
    } else if (t < 64) {
        size_t base = (size_t)bh * 32 * 64 + t;
        float run = 0.f;
#pragma unroll
        for (int c = 0; c < 32; ++c) {
            float cur = Zc[base + (size_t)c * 64];
            Zc[base + (size_t)c * 64] = run;
            run += cur;
        }
    }
}

// ---------------------------------------------------------------------------
// Per (head,chunk): P = tril(Q K^T); den = rowsum(P)+Q.z_pre;
// num = P@V + Q@S_pre^T; out = num/den written IN PLACE over the Q plane
// (vectorized via LDS re-stage; block's out region is contiguous 16 KB).
// ---------------------------------------------------------------------------
__global__ __launch_bounds__(256, 1) void attn_out_k(
    const u16* Qh, const u16* __restrict__ Kh,
    const u16* __restrict__ Vh, const u16* __restrict__ Sp,
    const float* __restrict__ Zp, u16* Qw)
{
    __shared__ __align__(16) u16 vtSh[64 * 136];   // V^T, +8 pad
    __shared__ __align__(16) u16 pSh[128 * 136];   // P; reused as out staging
    __shared__ float psum[128];
    __shared__ float qzs[128];
    int t = threadIdx.x, lane = t & 63, w = t >> 6;
    int q = lane >> 4, ln = lane & 15;
    int bhc = blockIdx.x, bh = bhc >> 5, ch = bhc & 31;
    const u16* Qb = Qh + ((size_t)bh * SEQ + (size_t)ch * CHUNK) * HD;
    const u16* Kb = Kh + ((size_t)bh * SEQ + (size_t)ch * CHUNK) * HD;
    const u16* Vb = Vh + ((size_t)bh * SEQ + (size_t)ch * CHUNK) * HD;
    const u16* Spb = Sp + (size_t)bhc * HD * HD;   // S^T[e][d]
    const float* Zpb = Zp + (size_t)bhc * HD;

    // stage V^T
#pragma unroll
    for (int i = 0; i < 4; ++i) {
        int g = i * 256 + t;
        int k = g >> 3, e0 = (g & 7) * 8;
        bf16x8 vv = *(const bf16x8*)&Vb[(size_t)k * HD + e0];
#pragma unroll
        for (int j = 0; j < 8; ++j) vtSh[(e0 + j) * 136 + k] = (u16)vv[j];
    }

    // GEMM1: scores = Q K^T, fragments straight from global
    int wm = (w & 1) * 64, wn = (w >> 1) * 64;
    bf16x8 afr[2][4];  // kept for Q@S_pre later
#pragma unroll
    for (int ks = 0; ks < 2; ++ks)
#pragma unroll
        for (int tm = 0; tm < 4; ++tm) {
            int m = wm + tm * 16 + ln;
            afr[ks][tm] = *(const bf16x8*)&Qb[(size_t)m * HD + ks * 32 + q * 8];
        }
    floatx4 acc[4][4] = {};
#pragma unroll
    for (int ks = 0; ks < 2; ++ks) {
        bf16x8 bfr[4];
#pragma unroll
        for (int tn = 0; tn < 4; ++tn) {
            int n = wn + tn * 16 + ln;
            bfr[tn] = *(const bf16x8*)&Kb[(size_t)n * HD + ks * 32 + q * 8];
        }
#pragma unroll
        for (int tm = 0; tm < 4; ++tm)
#pragma unroll
            for (int tn = 0; tn < 4; ++tn)
                acc[tm][tn] = __builtin_amdgcn_mfma_f32_16x16x32_bf16(
                    afr[ks][tm], bfr[tn], acc[tm][tn], 0, 0, 0);
    }
    // mask + write P
#pragma unroll
    for (int tm = 0; tm < 4; ++tm) {
        int rb = wm + tm * 16 + q * 4;
#pragma unroll
        for (int tn = 0; tn < 4; ++tn) {
            int cc = wn + tn * 16 + ln;
#pragma unroll
            for (int r = 0; r < 4; ++r) {
                float v = (cc <= rb + r) ? acc[tm][tn][r] : 0.f;
                pSh[(rb + r) * 136 + cc] = f2bf(v);
            }
        }
    }
    __syncthreads();
    // den parts
    if (t < 128) {
        const u16* prow = &pSh[t * 136];
        float s = 0.f;
#pragma unroll
        for (int i = 0; i < 16; ++i) {
            bf16x8 pv = *(const bf16x8*)&prow[i * 8];
#pragma unroll
            for (int j = 0; j < 8; ++j) s += bf2f((u16)pv[j]);
        }
        psum[t] = s;
    } else {
        int row = t - 128;
        float s = 0.f;
#pragma unroll
        for (int i = 0; i < 8; ++i) {
            bf16x8 qv = *(const bf16x8*)&Qb[(size_t)row * HD + i * 8];
#pragma unroll
            for (int j = 0; j < 8; ++j) s += bf2f((u16)qv[j]) * Zpb[i * 8 + j];
        }
        qzs[row] = s;
    }
    __syncthreads();

    // GEMM2: num = P @ V (K=128) + Q @ S_pre (K=64, S^T rows = vector loads)
    int wn2 = (w >> 1) * 32;
    floatx4 acc2[4][2] = {};
#pragma unroll
    for (int ks = 0; ks < 4; ++ks) {
        bf16x8 ap[4], bv[2];
#pragma unroll
        for (int tm = 0; tm < 4; ++tm) {
            int m = wm + tm * 16 + ln;
            ap[tm] = *(const bf16x8*)&pSh[m * 136 + ks * 32 + q * 8];
        }
#pragma unroll
        for (int tn = 0; tn < 2; ++tn) {
            int n = wn2 + tn * 16 + ln;
            bv[tn] = *(const bf16x8*)&vtSh[n * 136 + ks * 32 + q * 8];
        }
#pragma unroll
        for (int tm = 0; tm < 4; ++tm)
#pragma unroll
            for (int tn = 0; tn < 2; ++tn)
                acc2[tm][tn] = __builtin_amdgcn_mfma_f32_16x16x32_bf16(
                    ap[tm], bv[tn], acc2[tm][tn], 0, 0, 0);
    }
#pragma unroll
    for (int ks = 0; ks < 2; ++ks) {
        bf16x8 bs[2];
#pragma unroll
        for (int tn = 0; tn < 2; ++tn) {
            int n = wn2 + tn * 16 + ln;        // e
            bs[tn] = *(const bf16x8*)&Spb[(size_t)n * HD + ks * 32 + q * 8];
        }
#pragma unroll
        for (int tm = 0; tm < 4; ++tm)
#pragma unroll
            for (int tn = 0; tn < 2; ++tn)
                acc2[tm][tn] = __builtin_amdgcn_mfma_f32_16x16x32_bf16(
                    afr[ks][tm], bs[tn], acc2[tm][tn], 0, 0, 0);
    }
    // epilogue: divide, re-stage via LDS (stride 72 u16, 16B-aligned rows),
    // then fully-coalesced 16B stores into the contiguous 16KB out region.
    __syncthreads();   // GEMM2 pSh reads complete before overwrite
#pragma unroll
    for (int tm = 0; tm < 4; ++tm) {
        int rb = wm + tm * 16 + q * 4;
#pragma unroll
        for (int r = 0; r < 4; ++r) {
            int mrow = rb + r;
            float inv = 1.0f / fmaxf(psum[mrow] + qzs[mrow], 1e-20f);
#pragma unroll
            for (int tn = 0; tn < 2; ++tn) {
                int e = wn2 + tn * 16 + ln;
                pSh[mrow * 72 + e] = f2bf(acc2[tm][tn][r] * inv);
            }
        }
    }
    __syncthreads();
    size_t obase = ((size_t)bh * SEQ + (size_t)ch * CHUNK) * HD;
#pragma unroll
    for (int j = 0; j < 4; ++j) {
        int ci = j * 256 + t;                 // 16B chunk index, 0..1023
        *(bf16x8*)&Qw[obase + (size_t)ci * 8] =
            *(const bf16x8*)&pSh[(ci >> 3) * 72 + (ci & 7) * 8];
    }
}

extern "C" void kernel_launch(void* const* d_in, const int* in_sizes, int n_in,
                              void* d_out, int out_size, void* d_ws, size_t ws_size,
                              hipStream_t stream) {
    const float* x  = (const float*)d_in[0];
    const float* Wq = (const float*)d_in[1];
    const float* bq = (const float*)d_in[2];
    const float* Wk = (const float*)d_in[3];
    const float* bk = (const float*)d_in[4];
    const float* Wv = (const float*)d_in[5];
    const float* bv = (const float*)d_in[6];
    const float* Wo = (const float*)d_in[7];
    const float* bo = (const float*)d_in[8];
    float* out = (float*)d_out;

    const size_t PLANE = (size_t)NH * SEQ * HD;
    const size_t FIXED = (3 * (size_t)DM * DM + (size_t)DM * DM) * 2;
    const size_t PER_BATCH = 4 * PLANE * 2 + (size_t)NH * 32 * 4096 * 2
                           + (size_t)NH * 32 * HD * 4;
    if (ws_size < FIXED + PER_BATCH) return;
    int nb = (ws_size >= FIXED + 4 * PER_BATCH) ? 4
           : (ws_size >= FIXED + 2 * PER_BATCH) ? 2 : 1;

    char* p0 = (char*)d_ws;
    u16* Wqkv = (u16*)p0;                       p0 += 3 * (size_t)DM * DM * 2;
    u16* Wob  = (u16*)p0;                       p0 += (size_t)DM * DM * 2;

    cvt_w_k<<<dim3(2048), dim3(256), 0, stream>>>(Wq, Wk, Wv, Wo, Wqkv, Wob);

    for (int b0 = 0; b0 < 4; b0 += nb) {
        char* p = p0;
        u16* xb = (u16*)p;  p += (size_t)nb * PLANE * 2;
        u16* Qh = (u16*)p;  p += (size_t)nb * PLANE * 2;
        u16* Kh = (u16*)p;  p += (size_t)nb * PLANE * 2;
        u16* Vh = (u16*)p;  p += (size_t)nb * PLANE * 2;
        u16* Sc = (u16*)p;  p += (size_t)nb * NH * 32 * 4096 * 2;
        float* Zc = (float*)p;
        const float* xs = x + (size_t)b0 * SEQ * DM;

        cvt_x_k<<<dim3(nb * 2048), dim3(256), 0, stream>>>(xs, xb);
        qkv_gemm_k<<<dim3(24, nb * 32), dim3(256), 0, stream>>>(
            xb, Wqkv, bq, bk, bv, Qh, Kh, Vh);
        chunk_stats_k<<<dim3(nb * 512), dim3(256), 0, stream>>>(Kh, Vh, Sc, Zc);
        prefix_k<<<dim3(nb * 16, 33), dim3(128), 0, stream>>>(Sc, Zc);
        attn_out_k<<<dim3(nb * 512), dim3(256), 0, stream>>>(Qh, Kh, Vh, Sc, Zc, Qh);
        out_gemm_k<<<dim3(8, nb * 32), dim3(256), 0, stream>>>(
            Qh, Wob, bo, out + (size_t)b0 * SEQ * DM);
    }
}